// Round 18
// baseline (80.267 us; speedup 1.0000x reference)
//
#include <hip/hip_runtime.h>
#include <hip/hip_fp16.h>
#include <math.h>

#define IN_DIM 128
#define HID    128
#define NN     100000
#define WPACK_BYTES (64 * 64 * 16)       // 64 frags x 64 lanes x 16B = 64 KB
#define WPACK_OFF   64
#define UBF_OFF     (WPACK_OFF + WPACK_BYTES + 192)   // 256-aligned
#define UBF_BYTES   (NN * HID)                        // 12.8 MB (fp8)
#define VBF_OFF     (UBF_OFF + UBF_BYTES)
#define VBF_BYTES   (NN * HID)                        // 12.8 MB (fp8)

typedef __attribute__((ext_vector_type(8))) __bf16 bf16x8;
typedef __attribute__((ext_vector_type(4))) float  f32x4;
typedef __attribute__((ext_vector_type(2))) float  f32x2;

__device__ __forceinline__ unsigned pk2bf(float a, float b) {
    union { __bf16 h[2]; unsigned u; } r;
    r.h[0] = (__bf16)a; r.h[1] = (__bf16)b;   // v_cvt_pk_bf16_f32
    return r.u;
}
__device__ __forceinline__ bf16x8 asbf(uint4 v) { return __builtin_bit_cast(bf16x8, v); }

// dtype probe (block 0) + W1 -> bf16 B-fragment pack, 16 blocks x 4 frags.
__global__ void prep(const float* __restrict__ W1,
                     const unsigned* __restrict__ ei,
                     uint4* __restrict__ wpack,
                     int* __restrict__ flag, int do_pack) {
    const int t = threadIdx.x;
    if (blockIdx.x == 0 && t < 64) {
        unsigned v = ei[2 * t + 1];
        unsigned long long b = __ballot(v != 0u);
        if (t == 0) flag[0] = (b == 0ull) ? 1 : 0;
    }
    if (!do_pack) return;
    const int lane = t & 63;
    const int frag = (t >> 6) + blockIdx.x * 4;      // grid 16 -> frags 0..63
    const int kc = frag >> 3, jsg = frag & 7;
    const int k0 = kc * 32 + (lane >> 4) * 8;
    const int j  = jsg * 16 + (lane & 15);
    unsigned wv[4];
    #pragma unroll
    for (int p = 0; p < 4; ++p)
        wv[p] = pk2bf(W1[(k0 + 2 * p) * HID + j], W1[(k0 + 2 * p + 1) * HID + j]);
    wpack[frag * 64 + lane] = make_uint4(wv[0], wv[1], wv[2], wv[3]);
}

// uv_gemm v7: quadrant-per-BLOCK, W in 16KB LDS, one tile per wave.
// R17 diagnosis: 64-VGPR register-resident Bf capped occupancy at 16
// waves/CU while each wave sat on one long L2->MFMA chain (84% idle).
// Here block (tg, qd) stages ONE W quadrant (uv=qd>>1, jh=qd&1, 16KB)
// into LDS; its 4 waves each compute a DIFFERENT tile (wt = tg*4 + w)
// for that quadrant. Per-wave math identical to R17 (R16 coverage lesson:
// every (tile, quadrant) pair hit exactly once — tile->(tg,w), qd->block).
// VGPR ~50 (<=64 band -> 8 waves/SIMD); B via independent ds_read_b128.
// Cost: z read 4x logically (~200MB, L3-served) — traded against idle.
// UV row = 128B fp8; byte jh*64 + l4*4 + jsg = col j = jh*64 + jsg*16 + l4.
__global__ __launch_bounds__(256)
void uv_gemm(const float* __restrict__ z,
             const uint4* __restrict__ wpack,
             char* __restrict__ ubf, char* __restrict__ vbf,
             int nwt)
{
    __shared__ uint4 Wlds[16 * 64];     // 16 frags x 64 lanes x 16B = 16 KB
    const int t = threadIdx.x, lane = t & 63, w = t >> 6;
    const int l4 = lane & 15, q = lane >> 4;
    const int tg = blockIdx.x >> 2;
    const int qd = blockIdx.x & 3;
    const int uv = qd >> 1, jh = qd & 1;
    char* obuf = uv ? vbf : ubf;

    // stage this block's quadrant: 1024 uint4 = 256 threads x 4
    #pragma unroll
    for (int i = 0; i < 4; ++i) {
        const int idx = i * 256 + t;
        const int fi = idx >> 6, ln = idx & 63;      // frag-in-quadrant, lane
        const int kc = fi >> 2, jsg = fi & 3;
        Wlds[fi * 64 + ln] =
            wpack[(((uv * 4 + kc) * 8) + jh * 4 + jsg) * 64 + ln];
    }
    __syncthreads();

    const int wt = tg * 4 + w;
    if (wt >= nwt) return;
    const int node0 = wt * 16;                        // NN % 16 == 0
    const float* zr = z + (long long)(node0 + l4) * IN_DIM + q * 8;

    f32x4 acc[4] = {};
    #pragma unroll
    for (int kc = 0; kc < 4; ++kc) {
        const float4 f0 = *reinterpret_cast<const float4*>(zr + kc * 32);
        const float4 f1 = *reinterpret_cast<const float4*>(zr + kc * 32 + 4);
        const bf16x8 a = asbf(make_uint4(pk2bf(f0.x, f0.y), pk2bf(f0.z, f0.w),
                                         pk2bf(f1.x, f1.y), pk2bf(f1.z, f1.w)));
        #pragma unroll
        for (int jsg = 0; jsg < 4; ++jsg) {
            const uint4 b = Wlds[(kc * 4 + jsg) * 64 + lane];   // ds_read_b128
            acc[jsg] = __builtin_amdgcn_mfma_f32_16x16x32_bf16(
                a, asbf(b), acc[jsg], 0, 0, 0);
        }
    }

    // pack 4 jsg values -> 1 dword of e4m3; 16 lanes = 64B contiguous
    #pragma unroll
    for (int reg = 0; reg < 4; ++reg) {
        const int n = node0 + q * 4 + reg;
        int pk = __builtin_amdgcn_cvt_pk_fp8_f32(acc[0][reg], acc[1][reg], 0, false);
        pk = __builtin_amdgcn_cvt_pk_fp8_f32(acc[2][reg], acc[3][reg], pk, true);
        *reinterpret_cast<int*>(obuf + (long long)n * 128 + jh * 64 + l4 * 4) = pk;
    }
}

// Edge phase (R15-proven): streaming fp8 gather. Lane g reads 8B at byte g*8
// of each 128B row: dword.x = (l4=la, jsg0..3), dword.y = (l4=lb, jsg0..3),
// la = 2*(g&7), lb = la+1, jh = g>>3, col j = jh*64 + jsg*16 + l4.
__global__ __launch_bounds__(256)
void lp_edge(const char* __restrict__ ubf, const char* __restrict__ vbf,
             const int* __restrict__ ei32,
             const float* __restrict__ b1, const float* __restrict__ W2,
             const float* __restrict__ b2, float* __restrict__ out,
             const int* __restrict__ flag, int E)
{
    const int t = threadIdx.x;
    const int g = t & 15;
    const int use64 = flag[0];
    const int jh = g >> 3, la = 2 * (g & 7), lb = la + 1;

    f32x2 b1f[4], w2f[4];
    #pragma unroll
    for (int p = 0; p < 2; ++p) {
        const int l = p ? lb : la;
        b1f[2 * p]     = f32x2{b1[jh * 64 + l],      b1[jh * 64 + 16 + l]};
        b1f[2 * p + 1] = f32x2{b1[jh * 64 + 32 + l], b1[jh * 64 + 48 + l]};
        w2f[2 * p]     = f32x2{W2[jh * 64 + l],      W2[jh * 64 + 16 + l]};
        w2f[2 * p + 1] = f32x2{W2[jh * 64 + 32 + l], W2[jh * 64 + 48 + l]};
    }
    const f32x2 zf2 = {0.f, 0.f};
    const float b2v = b2[0];

// macro locals q0..q3 — must not collide with caller names (R14 lesson)
#define EDOT(ACC, UU, VV)                                                     \
    {                                                                         \
        f32x2 q0 = __builtin_amdgcn_cvt_pk_f32_fp8(UU.x, false)               \
                 + __builtin_amdgcn_cvt_pk_f32_fp8(VV.x, false) + b1f[0];     \
        f32x2 q1 = __builtin_amdgcn_cvt_pk_f32_fp8(UU.x, true)                \
                 + __builtin_amdgcn_cvt_pk_f32_fp8(VV.x, true) + b1f[1];      \
        f32x2 q2 = __builtin_amdgcn_cvt_pk_f32_fp8(UU.y, false)               \
                 + __builtin_amdgcn_cvt_pk_f32_fp8(VV.y, false) + b1f[2];     \
        f32x2 q3 = __builtin_amdgcn_cvt_pk_f32_fp8(UU.y, true)                \
                 + __builtin_amdgcn_cvt_pk_f32_fp8(VV.y, true) + b1f[3];      \
        q0 = __builtin_elementwise_max(q0, zf2);                              \
        q1 = __builtin_elementwise_max(q1, zf2);                              \
        q2 = __builtin_elementwise_max(q2, zf2);                              \
        q3 = __builtin_elementwise_max(q3, zf2);                              \
        ACC = fmaf(q0.x, w2f[0].x, fmaf(q0.y, w2f[0].y, ACC));                \
        ACC = fmaf(q1.x, w2f[1].x, fmaf(q1.y, w2f[1].y, ACC));                \
        ACC = fmaf(q2.x, w2f[2].x, fmaf(q2.y, w2f[2].y, ACC));                \
        ACC = fmaf(q3.x, w2f[3].x, fmaf(q3.y, w2f[3].y, ACC));                \
    }

    for (int e2 = blockIdx.x * 32 + ((t >> 4) << 1); e2 < E; e2 += gridDim.x * 32) {
        const int e3 = min(e2 + 1, E - 1);
        int s0 = ei32[(long long)e2 << use64];
        int d0 = ei32[(long long)(E + e2) << use64];
        int s1 = ei32[(long long)e3 << use64];
        int d1 = ei32[(long long)(E + e3) << use64];
        s0 = min(max(s0, 0), NN - 1); d0 = min(max(d0, 0), NN - 1);
        s1 = min(max(s1, 0), NN - 1); d1 = min(max(d1, 0), NN - 1);
        const uint2 uu0 = *reinterpret_cast<const uint2*>(ubf + (long long)s0 * 128 + g * 8);
        const uint2 vv0 = *reinterpret_cast<const uint2*>(vbf + (long long)d0 * 128 + g * 8);
        const uint2 uu1 = *reinterpret_cast<const uint2*>(ubf + (long long)s1 * 128 + g * 8);
        const uint2 vv1 = *reinterpret_cast<const uint2*>(vbf + (long long)d1 * 128 + g * 8);

        float sum0 = 0.f, sum1 = 0.f;
        EDOT(sum0, uu0, vv0)
        EDOT(sum1, uu1, vv1)

        #pragma unroll
        for (int o = 1; o <= 8; o <<= 1) {
            sum0 += __shfl_xor(sum0, o);
            sum1 += __shfl_xor(sum1, o);
        }
        if (g < 2) {
            const int e = e2 + g;
            if (e < E && (g == 0 || e3 == e2 + 1))
                out[e] = 1.f / (1.f + expf(-((g ? sum1 : sum0) + b2v)));
        }
    }
#undef EDOT
}

// ---------------- fallback (R5-proven fp32-gather kernel) ----------------
__global__ __launch_bounds__(256, 3)
void lp_main(const float* __restrict__ z,
             const int* __restrict__ ei32,
             const float* __restrict__ W1,
             const float* __restrict__ b1,
             const float* __restrict__ W2,
             const float* __restrict__ b2,
             float* __restrict__ out,
             const int* __restrict__ flag,
             const uint4* __restrict__ wpack,
             int use_ws, int E, int ntiles)
{
    __shared__ uint4 ldsA_[64 * 512 / 16];
    __shared__ float part[4][64];
    char* ldsc = (char*)ldsA_;

    const int t = threadIdx.x, lane = t & 63, w = t >> 6;
    const int use64 = flag[0];

    uint4 Bf[8][2];
    if (use_ws) {
        #pragma unroll
        for (int kc = 0; kc < 8; ++kc)
            #pragma unroll
            for (int js = 0; js < 2; ++js)
                Bf[kc][js] = wpack[(kc * 8 + (w * 2 + js)) * 64 + lane];
    } else {
        #pragma unroll
        for (int kc = 0; kc < 8; ++kc)
            #pragma unroll
            for (int js = 0; js < 2; ++js) {
                const int k0 = kc * 32 + (lane >> 4) * 8;
                const int j  = (w * 2 + js) * 16 + (lane & 15);
                unsigned wv[4];
                #pragma unroll
                for (int p = 0; p < 4; ++p)
                    wv[p] = pk2bf(W1[(k0 + 2 * p) * HID + j],
                                  W1[(k0 + 2 * p + 1) * HID + j]);
                Bf[kc][js] = make_uint4(wv[0], wv[1], wv[2], wv[3]);
            }
    }

    const int e_r = lane & 15, q = lane >> 4, m16 = q * 16;
    const float b1v0 = b1[w * 32 + e_r], b1v1 = b1[w * 32 + 16 + e_r];
    const float w2v0 = W2[w * 32 + e_r], w2v1 = W2[w * 32 + 16 + e_r];
    const float b2v  = b2[0];

    for (int tile = blockIdx.x; tile < ntiles; tile += gridDim.x) {
        const int e0 = tile * 64;
        #pragma unroll 8
        for (int i = 0; i < 16; ++i) {
            const int el = i * 4 + w;
            int e = e0 + el; if (e > E - 1) e = E - 1;
            const int word = (lane < 32) ? e : (E + e);
            int node = ei32[(long long)word << use64];
            node = min(max(node, 0), NN - 1);
            const float4 v = *reinterpret_cast<const float4*>(
                &z[node * IN_DIM + (lane & 31) * 4]);
            const int byte = el * 512 + ((lane * 8) ^ ((el & 7) << 4));
            *reinterpret_cast<uint2*>(ldsc + byte) =
                make_uint2(pk2bf(v.x, v.y), pk2bf(v.z, v.w));
        }
        __syncthreads();

        f32x4 acc[4][2] = {};
        #pragma unroll
        for (int kc = 0; kc < 8; ++kc) {
            #pragma unroll
            for (int es = 0; es < 4; ++es) {
                const int row  = es * 16 + e_r;
                const int byte = row * 512 + ((kc * 64 + m16) ^ ((row & 7) << 4));
                const bf16x8 a = *reinterpret_cast<const bf16x8*>(ldsc + byte);
                acc[es][0] = __builtin_amdgcn_mfma_f32_16x16x32_bf16(
                    a, asbf(Bf[kc][0]), acc[es][0], 0, 0, 0);
                acc[es][1] = __builtin_amdgcn_mfma_f32_16x16x32_bf16(
                    a, asbf(Bf[kc][1]), acc[es][1], 0, 0, 0);
            }
        }

        float v16[16];
        #pragma unroll
        for (int es = 0; es < 4; ++es)
            #pragma unroll
            for (int reg = 0; reg < 4; ++reg)
                v16[es * 4 + reg] = fmaxf(acc[es][0][reg] + b1v0, 0.f) * w2v0
                                  + fmaxf(acc[es][1][reg] + b1v1, 0.f) * w2v1;
        #pragma unroll
        for (int rnd = 0; rnd < 4; ++rnd) {
            const int o = 1 << rnd, hl = 8 >> rnd;
            #pragma unroll
            for (int i = 0; i < hl; ++i) {
                const float a = v16[i], b = v16[i + hl];
                const float s = (lane & o) ? a : b;
                const float r = __shfl_xor(s, o);
                v16[i] = ((lane & o) ? b : a) + r;
            }
        }
        {
            const int lx  = lane & 15;
            const int idx = ((lx & 1) << 3) | ((lx & 2) << 1) | ((lx & 4) >> 1) | ((lx & 8) >> 3);
            const int edge = (idx >> 2) * 16 + q * 4 + (idx & 3);
            part[w][edge] = v16[0];
        }
        __syncthreads();

        if (t < 64) {
            const int e = e0 + t;
            if (e < E) {
                const float s = part[0][t] + part[1][t] + part[2][t] + part[3][t] + b2v;
                out[e] = 1.f / (1.f + expf(-s));
            }
        }
    }
}

extern "C" void kernel_launch(void* const* d_in, const int* in_sizes, int n_in,
                              void* d_out, int out_size, void* d_ws, size_t ws_size,
                              hipStream_t stream) {
    const float* z  = (const float*)d_in[0];
    const void*  ei = d_in[1];
    const float* W1 = (const float*)d_in[2];
    const float* b1 = (const float*)d_in[3];
    const float* W2 = (const float*)d_in[4];
    const float* b2 = (const float*)d_in[5];
    float* out = (float*)d_out;
    int*   flag  = (int*)d_ws;
    uint4* wpack = (uint4*)((char*)d_ws + WPACK_OFF);
    char*  ubf   = (char*)d_ws + UBF_OFF;
    char*  vbf   = (char*)d_ws + VBF_OFF;

    const int E = in_sizes[1] / 2;
    const int use_ws = (ws_size >= (size_t)(WPACK_OFF + WPACK_BYTES)) ? 1 : 0;
    const int use_uv = (ws_size >= (size_t)(VBF_OFF + VBF_BYTES)) ? 1 : 0;

    hipLaunchKernelGGL(prep, dim3(16), dim3(256), 0, stream,
                       W1, (const unsigned*)ei, wpack, flag, use_ws);

    if (use_uv) {
        const int nwt = NN / 16;                           // 6250 tiles
        const int ngrp = (nwt + 3) / 4;                    // 1563 tile-groups
        hipLaunchKernelGGL(uv_gemm, dim3(ngrp * 4), dim3(256), 0, stream,
                           z, wpack, ubf, vbf, nwt);
        hipLaunchKernelGGL(lp_edge, dim3(2048), dim3(256), 0, stream,
                           ubf, vbf, (const int*)ei, b1, W2, b2, out, flag, E);
    } else {
        const int ntiles = (E + 63) / 64;
        const int grid = (ntiles < 768) ? ntiles : 768;
        hipLaunchKernelGGL(lp_main, dim3(grid), dim3(256), 0, stream,
                           z, (const int*)ei, W1, b1, W2, b2, out, flag, wpack,
                           use_ws, E, ntiles);
    }
}

// Round 19
// 69.717 us; speedup vs baseline: 1.1513x; 1.1513x over previous
//
#include <hip/hip_runtime.h>
#include <hip/hip_fp16.h>
#include <math.h>

#define IN_DIM 128
#define HID    128
#define NN     100000
#define WPACK_BYTES (64 * 64 * 16)       // 64 frags x 64 lanes x 16B = 64 KB
#define WPACK_OFF   64
#define UBF_OFF     (WPACK_OFF + WPACK_BYTES + 192)   // 256-aligned
#define UBF_BYTES   (NN * HID)                        // 12.8 MB (fp8)
#define VBF_OFF     (UBF_OFF + UBF_BYTES)
#define VBF_BYTES   (NN * HID)                        // 12.8 MB (fp8)

typedef __attribute__((ext_vector_type(8))) __bf16 bf16x8;
typedef __attribute__((ext_vector_type(4))) float  f32x4;
typedef __attribute__((ext_vector_type(2))) float  f32x2;

__device__ __forceinline__ unsigned pk2bf(float a, float b) {
    union { __bf16 h[2]; unsigned u; } r;
    r.h[0] = (__bf16)a; r.h[1] = (__bf16)b;   // v_cvt_pk_bf16_f32
    return r.u;
}
__device__ __forceinline__ bf16x8 asbf(uint4 v) { return __builtin_bit_cast(bf16x8, v); }

// dtype probe (block 0) + W1 -> bf16 B-fragment pack, 16 blocks x 4 frags.
__global__ void prep(const float* __restrict__ W1,
                     const unsigned* __restrict__ ei,
                     uint4* __restrict__ wpack,
                     int* __restrict__ flag, int do_pack) {
    const int t = threadIdx.x;
    if (blockIdx.x == 0 && t < 64) {
        unsigned v = ei[2 * t + 1];
        unsigned long long b = __ballot(v != 0u);
        if (t == 0) flag[0] = (b == 0ull) ? 1 : 0;
    }
    if (!do_pack) return;
    const int lane = t & 63;
    const int frag = (t >> 6) + blockIdx.x * 4;      // grid 16 -> frags 0..63
    const int kc = frag >> 3, jsg = frag & 7;
    const int k0 = kc * 32 + (lane >> 4) * 8;
    const int j  = jsg * 16 + (lane & 15);
    unsigned wv[4];
    #pragma unroll
    for (int p = 0; p < 4; ++p)
        wv[p] = pk2bf(W1[(k0 + 2 * p) * HID + j], W1[(k0 + 2 * p + 1) * HID + j]);
    wpack[frag * 64 + lane] = make_uint4(wv[0], wv[1], wv[2], wv[3]);
}

// uv_gemm v8: HALF-per-block (R18's quadrant-per-block read z 4x = 200MB
// fabric ~= 30us — the entire kernel cost). Block b: buffer hb = b&1 (U|V),
// tile-group tg = b>>1; wave w computes tile tg*4+w for BOTH jh halves.
// W staged: 32 frags = 32KB LDS (5 blocks/CU); acc[2][4] = 32 VGPR.
// z traffic 2x = 100MB. Coverage: (tile,buffer) <-> ((tg,w), hb), each once.
// UV row = 128B fp8; byte jh*64 + l4*4 + jsg = col j = jh*64 + jsg*16 + l4.
__global__ __launch_bounds__(256)
void uv_gemm(const float* __restrict__ z,
             const uint4* __restrict__ wpack,
             char* __restrict__ ubf, char* __restrict__ vbf,
             int nwt)
{
    __shared__ uint4 Wlds[32 * 64];     // 32 frags x 64 lanes x 16B = 32 KB
    const int t = threadIdx.x, lane = t & 63, w = t >> 6;
    const int l4 = lane & 15, q = lane >> 4;
    const int tg = blockIdx.x >> 1;
    const int hb = blockIdx.x & 1;
    char* obuf = hb ? vbf : ubf;

    // stage this buffer-half's 32 frags: fi = kc*8 + jh*4 + jsg = kc*8 + (fi&7)
    #pragma unroll
    for (int i = 0; i < 8; ++i) {
        const int idx = i * 256 + t;
        const int fi = idx >> 6, ln = idx & 63;
        const int kc = fi >> 3;
        Wlds[fi * 64 + ln] = wpack[((hb * 4 + kc) * 8 + (fi & 7)) * 64 + ln];
    }
    __syncthreads();

    const int wt = tg * 4 + w;
    if (wt >= nwt) return;
    const int node0 = wt * 16;                        // NN % 16 == 0
    const float* zr = z + (long long)(node0 + l4) * IN_DIM + q * 8;

    f32x4 acc[2][4] = {};
    #pragma unroll
    for (int kc = 0; kc < 4; ++kc) {
        const float4 f0 = *reinterpret_cast<const float4*>(zr + kc * 32);
        const float4 f1 = *reinterpret_cast<const float4*>(zr + kc * 32 + 4);
        const bf16x8 a = asbf(make_uint4(pk2bf(f0.x, f0.y), pk2bf(f0.z, f0.w),
                                         pk2bf(f1.x, f1.y), pk2bf(f1.z, f1.w)));
        #pragma unroll
        for (int jh = 0; jh < 2; ++jh)
            #pragma unroll
            for (int jsg = 0; jsg < 4; ++jsg) {
                const uint4 b = Wlds[(kc * 8 + jh * 4 + jsg) * 64 + lane];
                acc[jh][jsg] = __builtin_amdgcn_mfma_f32_16x16x32_bf16(
                    a, asbf(b), acc[jh][jsg], 0, 0, 0);
            }
    }

    // pack 4 jsg values -> 1 dword of e4m3 per (reg, jh); 16 lanes = 64B
    #pragma unroll
    for (int reg = 0; reg < 4; ++reg) {
        const int n = node0 + q * 4 + reg;
        #pragma unroll
        for (int jh = 0; jh < 2; ++jh) {
            int pk = __builtin_amdgcn_cvt_pk_fp8_f32(acc[jh][0][reg], acc[jh][1][reg], 0, false);
            pk = __builtin_amdgcn_cvt_pk_fp8_f32(acc[jh][2][reg], acc[jh][3][reg], pk, true);
            *reinterpret_cast<int*>(obuf + (long long)n * 128 + jh * 64 + l4 * 4) = pk;
        }
    }
}

// Edge phase: streaming fp8 gather, 4 edges per 16-lane group (8 loads in
// flight/lane), packed-f32 accumulate (v_pk_fma_f32). Lane g reads 8B at
// byte g*8 of each 128B row; layout as R15 (col j = jh*64 + jsg*16 + l4).
__global__ __launch_bounds__(256)
void lp_edge(const char* __restrict__ ubf, const char* __restrict__ vbf,
             const int* __restrict__ ei32,
             const float* __restrict__ b1, const float* __restrict__ W2,
             const float* __restrict__ b2, float* __restrict__ out,
             const int* __restrict__ flag, int E)
{
    const int t = threadIdx.x;
    const int g = t & 15;
    const int use64 = flag[0];
    const int jh = g >> 3, la = 2 * (g & 7), lb = la + 1;

    f32x2 b1f[4], w2f[4];
    #pragma unroll
    for (int p = 0; p < 2; ++p) {
        const int l = p ? lb : la;
        b1f[2 * p]     = f32x2{b1[jh * 64 + l],      b1[jh * 64 + 16 + l]};
        b1f[2 * p + 1] = f32x2{b1[jh * 64 + 32 + l], b1[jh * 64 + 48 + l]};
        w2f[2 * p]     = f32x2{W2[jh * 64 + l],      W2[jh * 64 + 16 + l]};
        w2f[2 * p + 1] = f32x2{W2[jh * 64 + 32 + l], W2[jh * 64 + 48 + l]};
    }
    const f32x2 zf2 = {0.f, 0.f};
    const float b2v = b2[0];

// macro locals q0..q3 (R14 lesson: no collision with caller names).
// ACC2 is f32x2; pairwise pk_fma, reduced .x+.y after the loop.
#define EDOT(ACC2, UU, VV)                                                    \
    {                                                                         \
        f32x2 q0 = __builtin_amdgcn_cvt_pk_f32_fp8(UU.x, false)               \
                 + __builtin_amdgcn_cvt_pk_f32_fp8(VV.x, false) + b1f[0];     \
        f32x2 q1 = __builtin_amdgcn_cvt_pk_f32_fp8(UU.x, true)                \
                 + __builtin_amdgcn_cvt_pk_f32_fp8(VV.x, true) + b1f[1];      \
        f32x2 q2 = __builtin_amdgcn_cvt_pk_f32_fp8(UU.y, false)               \
                 + __builtin_amdgcn_cvt_pk_f32_fp8(VV.y, false) + b1f[2];     \
        f32x2 q3 = __builtin_amdgcn_cvt_pk_f32_fp8(UU.y, true)                \
                 + __builtin_amdgcn_cvt_pk_f32_fp8(VV.y, true) + b1f[3];      \
        q0 = __builtin_elementwise_max(q0, zf2);                              \
        q1 = __builtin_elementwise_max(q1, zf2);                              \
        q2 = __builtin_elementwise_max(q2, zf2);                              \
        q3 = __builtin_elementwise_max(q3, zf2);                              \
        ACC2 = __builtin_elementwise_fma(q0, w2f[0], ACC2);                   \
        ACC2 = __builtin_elementwise_fma(q1, w2f[1], ACC2);                   \
        ACC2 = __builtin_elementwise_fma(q2, w2f[2], ACC2);                   \
        ACC2 = __builtin_elementwise_fma(q3, w2f[3], ACC2);                   \
    }

    for (int base = blockIdx.x * 64 + ((t >> 4) << 2); base < E; base += gridDim.x * 64) {
        int e[4], s[4], d[4];
        #pragma unroll
        for (int k = 0; k < 4; ++k) {
            e[k] = min(base + k, E - 1);
            s[k] = ei32[(long long)e[k] << use64];
            d[k] = ei32[(long long)(E + e[k]) << use64];
            s[k] = min(max(s[k], 0), NN - 1);
            d[k] = min(max(d[k], 0), NN - 1);
        }
        uint2 uu[4], vv[4];
        #pragma unroll
        for (int k = 0; k < 4; ++k) {
            uu[k] = *reinterpret_cast<const uint2*>(ubf + (long long)s[k] * 128 + g * 8);
            vv[k] = *reinterpret_cast<const uint2*>(vbf + (long long)d[k] * 128 + g * 8);
        }

        f32x2 a0 = zf2, a1 = zf2, a2 = zf2, a3 = zf2;
        EDOT(a0, uu[0], vv[0])
        EDOT(a1, uu[1], vv[1])
        EDOT(a2, uu[2], vv[2])
        EDOT(a3, uu[3], vv[3])
        float s0 = a0.x + a0.y, s1 = a1.x + a1.y;
        float s2 = a2.x + a2.y, s3 = a3.x + a3.y;

        #pragma unroll
        for (int o = 1; o <= 8; o <<= 1) {
            s0 += __shfl_xor(s0, o);
            s1 += __shfl_xor(s1, o);
            s2 += __shfl_xor(s2, o);
            s3 += __shfl_xor(s3, o);
        }
        if (g < 4) {
            const int eo = base + g;
            if (eo < E) {
                const float r = (g == 0) ? s0 : (g == 1) ? s1 : (g == 2) ? s2 : s3;
                out[eo] = 1.f / (1.f + expf(-(r + b2v)));
            }
        }
    }
#undef EDOT
}

// ---------------- fallback (R5-proven fp32-gather kernel) ----------------
__global__ __launch_bounds__(256, 3)
void lp_main(const float* __restrict__ z,
             const int* __restrict__ ei32,
             const float* __restrict__ W1,
             const float* __restrict__ b1,
             const float* __restrict__ W2,
             const float* __restrict__ b2,
             float* __restrict__ out,
             const int* __restrict__ flag,
             const uint4* __restrict__ wpack,
             int use_ws, int E, int ntiles)
{
    __shared__ uint4 ldsA_[64 * 512 / 16];
    __shared__ float part[4][64];
    char* ldsc = (char*)ldsA_;

    const int t = threadIdx.x, lane = t & 63, w = t >> 6;
    const int use64 = flag[0];

    uint4 Bf[8][2];
    if (use_ws) {
        #pragma unroll
        for (int kc = 0; kc < 8; ++kc)
            #pragma unroll
            for (int js = 0; js < 2; ++js)
                Bf[kc][js] = wpack[(kc * 8 + (w * 2 + js)) * 64 + lane];
    } else {
        #pragma unroll
        for (int kc = 0; kc < 8; ++kc)
            #pragma unroll
            for (int js = 0; js < 2; ++js) {
                const int k0 = kc * 32 + (lane >> 4) * 8;
                const int j  = (w * 2 + js) * 16 + (lane & 15);
                unsigned wv[4];
                #pragma unroll
                for (int p = 0; p < 4; ++p)
                    wv[p] = pk2bf(W1[(k0 + 2 * p) * HID + j],
                                  W1[(k0 + 2 * p + 1) * HID + j]);
                Bf[kc][js] = make_uint4(wv[0], wv[1], wv[2], wv[3]);
            }
    }

    const int e_r = lane & 15, q = lane >> 4, m16 = q * 16;
    const float b1v0 = b1[w * 32 + e_r], b1v1 = b1[w * 32 + 16 + e_r];
    const float w2v0 = W2[w * 32 + e_r], w2v1 = W2[w * 32 + 16 + e_r];
    const float b2v  = b2[0];

    for (int tile = blockIdx.x; tile < ntiles; tile += gridDim.x) {
        const int e0 = tile * 64;
        #pragma unroll 8
        for (int i = 0; i < 16; ++i) {
            const int el = i * 4 + w;
            int e = e0 + el; if (e > E - 1) e = E - 1;
            const int word = (lane < 32) ? e : (E + e);
            int node = ei32[(long long)word << use64];
            node = min(max(node, 0), NN - 1);
            const float4 v = *reinterpret_cast<const float4*>(
                &z[node * IN_DIM + (lane & 31) * 4]);
            const int byte = el * 512 + ((lane * 8) ^ ((el & 7) << 4));
            *reinterpret_cast<uint2*>(ldsc + byte) =
                make_uint2(pk2bf(v.x, v.y), pk2bf(v.z, v.w));
        }
        __syncthreads();

        f32x4 acc[4][2] = {};
        #pragma unroll
        for (int kc = 0; kc < 8; ++kc) {
            #pragma unroll
            for (int es = 0; es < 4; ++es) {
                const int row  = es * 16 + e_r;
                const int byte = row * 512 + ((kc * 64 + m16) ^ ((row & 7) << 4));
                const bf16x8 a = *reinterpret_cast<const bf16x8*>(ldsc + byte);
                acc[es][0] = __builtin_amdgcn_mfma_f32_16x16x32_bf16(
                    a, asbf(Bf[kc][0]), acc[es][0], 0, 0, 0);
                acc[es][1] = __builtin_amdgcn_mfma_f32_16x16x32_bf16(
                    a, asbf(Bf[kc][1]), acc[es][1], 0, 0, 0);
            }
        }

        float v16[16];
        #pragma unroll
        for (int es = 0; es < 4; ++es)
            #pragma unroll
            for (int reg = 0; reg < 4; ++reg)
                v16[es * 4 + reg] = fmaxf(acc[es][0][reg] + b1v0, 0.f) * w2v0
                                  + fmaxf(acc[es][1][reg] + b1v1, 0.f) * w2v1;
        #pragma unroll
        for (int rnd = 0; rnd < 4; ++rnd) {
            const int o = 1 << rnd, hl = 8 >> rnd;
            #pragma unroll
            for (int i = 0; i < hl; ++i) {
                const float a = v16[i], b = v16[i + hl];
                const float s = (lane & o) ? a : b;
                const float r = __shfl_xor(s, o);
                v16[i] = ((lane & o) ? b : a) + r;
            }
        }
        {
            const int lx  = lane & 15;
            const int idx = ((lx & 1) << 3) | ((lx & 2) << 1) | ((lx & 4) >> 1) | ((lx & 8) >> 3);
            const int edge = (idx >> 2) * 16 + q * 4 + (idx & 3);
            part[w][edge] = v16[0];
        }
        __syncthreads();

        if (t < 64) {
            const int e = e0 + t;
            if (e < E) {
                const float s = part[0][t] + part[1][t] + part[2][t] + part[3][t] + b2v;
                out[e] = 1.f / (1.f + expf(-s));
            }
        }
    }
}

extern "C" void kernel_launch(void* const* d_in, const int* in_sizes, int n_in,
                              void* d_out, int out_size, void* d_ws, size_t ws_size,
                              hipStream_t stream) {
    const float* z  = (const float*)d_in[0];
    const void*  ei = d_in[1];
    const float* W1 = (const float*)d_in[2];
    const float* b1 = (const float*)d_in[3];
    const float* W2 = (const float*)d_in[4];
    const float* b2 = (const float*)d_in[5];
    float* out = (float*)d_out;
    int*   flag  = (int*)d_ws;
    uint4* wpack = (uint4*)((char*)d_ws + WPACK_OFF);
    char*  ubf   = (char*)d_ws + UBF_OFF;
    char*  vbf   = (char*)d_ws + VBF_OFF;

    const int E = in_sizes[1] / 2;
    const int use_ws = (ws_size >= (size_t)(WPACK_OFF + WPACK_BYTES)) ? 1 : 0;
    const int use_uv = (ws_size >= (size_t)(VBF_OFF + VBF_BYTES)) ? 1 : 0;

    hipLaunchKernelGGL(prep, dim3(16), dim3(256), 0, stream,
                       W1, (const unsigned*)ei, wpack, flag, use_ws);

    if (use_uv) {
        const int nwt = NN / 16;                           // 6250 tiles
        const int ngrp = (nwt + 3) / 4;                    // 1563 tile-groups
        hipLaunchKernelGGL(uv_gemm, dim3(ngrp * 2), dim3(256), 0, stream,
                           z, wpack, ubf, vbf, nwt);
        hipLaunchKernelGGL(lp_edge, dim3(2048), dim3(256), 0, stream,
                           ubf, vbf, (const int*)ei, b1, W2, b2, out, flag, E);
    } else {
        const int ntiles = (E + 63) / 64;
        const int grid = (ntiles < 768) ? ntiles : 768;
        hipLaunchKernelGGL(lp_main, dim3(grid), dim3(256), 0, stream,
                           z, (const int*)ei, W1, b1, W2, b2, out, flag, wpack,
                           use_ws, E, ntiles);
    }
}

// Round 20
// 68.214 us; speedup vs baseline: 1.1767x; 1.0220x over previous
//
#include <hip/hip_runtime.h>
#include <hip/hip_fp16.h>
#include <math.h>

#define IN_DIM 128
#define HID    128
#define NN     100000
#define WPACK_BYTES (64 * 64 * 16)       // 64 frags x 64 lanes x 16B = 64 KB
#define WPACK_OFF   64
#define UBF_OFF     (WPACK_OFF + WPACK_BYTES + 192)   // 256-aligned
#define UBF_BYTES   (NN * HID)                        // 12.8 MB (fp8)
#define VBF_OFF     (UBF_OFF + UBF_BYTES)
#define VBF_BYTES   (NN * HID)                        // 12.8 MB (fp8)

typedef __attribute__((ext_vector_type(8))) __bf16 bf16x8;
typedef __attribute__((ext_vector_type(4))) float  f32x4;
typedef __attribute__((ext_vector_type(2))) float  f32x2;

__device__ __forceinline__ unsigned pk2bf(float a, float b) {
    union { __bf16 h[2]; unsigned u; } r;
    r.h[0] = (__bf16)a; r.h[1] = (__bf16)b;   // v_cvt_pk_bf16_f32
    return r.u;
}
__device__ __forceinline__ bf16x8 asbf(uint4 v) { return __builtin_bit_cast(bf16x8, v); }

// dtype probe (block 0) + W1 -> bf16 B-fragment pack, 16 blocks x 4 frags.
__global__ void prep(const float* __restrict__ W1,
                     const unsigned* __restrict__ ei,
                     uint4* __restrict__ wpack,
                     int* __restrict__ flag, int do_pack) {
    const int t = threadIdx.x;
    if (blockIdx.x == 0 && t < 64) {
        unsigned v = ei[2 * t + 1];
        unsigned long long b = __ballot(v != 0u);
        if (t == 0) flag[0] = (b == 0ull) ? 1 : 0;
    }
    if (!do_pack) return;
    const int lane = t & 63;
    const int frag = (t >> 6) + blockIdx.x * 4;      // grid 16 -> frags 0..63
    const int kc = frag >> 3, jsg = frag & 7;
    const int k0 = kc * 32 + (lane >> 4) * 8;
    const int j  = jsg * 16 + (lane & 15);
    unsigned wv[4];
    #pragma unroll
    for (int p = 0; p < 4; ++p)
        wv[p] = pk2bf(W1[(k0 + 2 * p) * HID + j], W1[(k0 + 2 * p + 1) * HID + j]);
    wpack[frag * 64 + lane] = make_uint4(wv[0], wv[1], wv[2], wv[3]);
}

// uv_gemm v8 (R19-proven): HALF-per-block, W in 32KB LDS, one tile per wave.
// UV row = 128B fp8; byte jh*64 + l4*4 + jsg = col j = jh*64 + jsg*16 + l4.
__global__ __launch_bounds__(256)
void uv_gemm(const float* __restrict__ z,
             const uint4* __restrict__ wpack,
             char* __restrict__ ubf, char* __restrict__ vbf,
             int nwt)
{
    __shared__ uint4 Wlds[32 * 64];     // 32 frags x 64 lanes x 16B = 32 KB
    const int t = threadIdx.x, lane = t & 63, w = t >> 6;
    const int l4 = lane & 15, q = lane >> 4;
    const int tg = blockIdx.x >> 1;
    const int hb = blockIdx.x & 1;
    char* obuf = hb ? vbf : ubf;

    #pragma unroll
    for (int i = 0; i < 8; ++i) {
        const int idx = i * 256 + t;
        const int fi = idx >> 6, ln = idx & 63;
        const int kc = fi >> 3;
        Wlds[fi * 64 + ln] = wpack[((hb * 4 + kc) * 8 + (fi & 7)) * 64 + ln];
    }
    __syncthreads();

    const int wt = tg * 4 + w;
    if (wt >= nwt) return;
    const int node0 = wt * 16;                        // NN % 16 == 0
    const float* zr = z + (long long)(node0 + l4) * IN_DIM + q * 8;

    f32x4 acc[2][4] = {};
    #pragma unroll
    for (int kc = 0; kc < 4; ++kc) {
        const float4 f0 = *reinterpret_cast<const float4*>(zr + kc * 32);
        const float4 f1 = *reinterpret_cast<const float4*>(zr + kc * 32 + 4);
        const bf16x8 a = asbf(make_uint4(pk2bf(f0.x, f0.y), pk2bf(f0.z, f0.w),
                                         pk2bf(f1.x, f1.y), pk2bf(f1.z, f1.w)));
        #pragma unroll
        for (int jh = 0; jh < 2; ++jh)
            #pragma unroll
            for (int jsg = 0; jsg < 4; ++jsg) {
                const uint4 b = Wlds[(kc * 8 + jh * 4 + jsg) * 64 + lane];
                acc[jh][jsg] = __builtin_amdgcn_mfma_f32_16x16x32_bf16(
                    a, asbf(b), acc[jh][jsg], 0, 0, 0);
            }
    }

    #pragma unroll
    for (int reg = 0; reg < 4; ++reg) {
        const int n = node0 + q * 4 + reg;
        #pragma unroll
        for (int jh = 0; jh < 2; ++jh) {
            int pk = __builtin_amdgcn_cvt_pk_fp8_f32(acc[jh][0][reg], acc[jh][1][reg], 0, false);
            pk = __builtin_amdgcn_cvt_pk_fp8_f32(acc[jh][2][reg], acc[jh][3][reg], pk, true);
            *reinterpret_cast<int*>(obuf + (long long)n * 128 + jh * 64 + l4 * 4) = pk;
        }
    }
}

// lp_edge v9: 8 lanes per edge, one uint4 (16B) per lane per row — 16
// gather requests/edge instead of 32 (R19 showed request-rate, not bytes,
// bound the gather). Lane g: bytes [g*16, g*16+16) of each 128B row ->
// jh = g>>2, dword d covers l4 = 4*(g&3)+d, jsg 0..3. 4 edges per group.
__global__ __launch_bounds__(256)
void lp_edge(const char* __restrict__ ubf, const char* __restrict__ vbf,
             const int* __restrict__ ei32,
             const float* __restrict__ b1, const float* __restrict__ W2,
             const float* __restrict__ b2, float* __restrict__ out,
             const int* __restrict__ flag, int E)
{
    const int t = threadIdx.x;
    const int g = t & 7;
    const int use64 = flag[0];
    const int jh = g >> 2;
    const int l0 = (g & 3) * 4;

    // coeff table: [d*2+p] -> (jsg 2p, 2p+1) at l4 = l0+d
    f32x2 b1f[8], w2f[8];
    #pragma unroll
    for (int d = 0; d < 4; ++d)
        #pragma unroll
        for (int p = 0; p < 2; ++p) {
            const int l = l0 + d;
            b1f[d * 2 + p] = f32x2{b1[jh * 64 + (2 * p) * 16 + l],
                                   b1[jh * 64 + (2 * p + 1) * 16 + l]};
            w2f[d * 2 + p] = f32x2{W2[jh * 64 + (2 * p) * 16 + l],
                                   W2[jh * 64 + (2 * p + 1) * 16 + l]};
        }
    const f32x2 zf2 = {0.f, 0.f};
    const float b2v = b2[0];

// macro locals qlo/qhi (R14 lesson: unique names vs caller's a0..a3)
#define EDOT_D(ACC2, UW, VW, D)                                              \
    {                                                                        \
        f32x2 qlo = __builtin_amdgcn_cvt_pk_f32_fp8(UW, false)               \
                  + __builtin_amdgcn_cvt_pk_f32_fp8(VW, false) + b1f[2*D];   \
        f32x2 qhi = __builtin_amdgcn_cvt_pk_f32_fp8(UW, true)                \
                  + __builtin_amdgcn_cvt_pk_f32_fp8(VW, true) + b1f[2*D+1];  \
        qlo = __builtin_elementwise_max(qlo, zf2);                           \
        qhi = __builtin_elementwise_max(qhi, zf2);                           \
        ACC2 = __builtin_elementwise_fma(qlo, w2f[2*D], ACC2);               \
        ACC2 = __builtin_elementwise_fma(qhi, w2f[2*D+1], ACC2);             \
    }
#define EDOT4(ACC2, UU, VV)                                                  \
    EDOT_D(ACC2, UU.x, VV.x, 0) EDOT_D(ACC2, UU.y, VV.y, 1)                  \
    EDOT_D(ACC2, UU.z, VV.z, 2) EDOT_D(ACC2, UU.w, VV.w, 3)

    // 32 groups/block x 4 edges = 128 edges per block-iteration
    for (int base = blockIdx.x * 128 + ((t >> 3) << 2); base < E;
         base += gridDim.x * 128) {
        int s[4], dn[4];
        #pragma unroll
        for (int k = 0; k < 4; ++k) {
            const int e = min(base + k, E - 1);
            s[k]  = min(max(ei32[(long long)e << use64], 0), NN - 1);
            dn[k] = min(max(ei32[(long long)(E + e) << use64], 0), NN - 1);
        }
        uint4 uu[4], vv[4];
        #pragma unroll
        for (int k = 0; k < 4; ++k) {
            uu[k] = *reinterpret_cast<const uint4*>(ubf + (long long)s[k]  * 128 + g * 16);
            vv[k] = *reinterpret_cast<const uint4*>(vbf + (long long)dn[k] * 128 + g * 16);
        }

        f32x2 a0 = zf2, a1 = zf2, a2 = zf2, a3 = zf2;
        EDOT4(a0, uu[0], vv[0])
        EDOT4(a1, uu[1], vv[1])
        EDOT4(a2, uu[2], vv[2])
        EDOT4(a3, uu[3], vv[3])
        float s0 = a0.x + a0.y, s1 = a1.x + a1.y;
        float s2 = a2.x + a2.y, s3 = a3.x + a3.y;

        #pragma unroll
        for (int o = 1; o <= 4; o <<= 1) {
            s0 += __shfl_xor(s0, o);
            s1 += __shfl_xor(s1, o);
            s2 += __shfl_xor(s2, o);
            s3 += __shfl_xor(s3, o);
        }
        if (g < 4) {
            const int eo = base + g;
            if (eo < E) {
                const float r = (g == 0) ? s0 : (g == 1) ? s1 : (g == 2) ? s2 : s3;
                out[eo] = 1.f / (1.f + expf(-(r + b2v)));
            }
        }
    }
#undef EDOT4
#undef EDOT_D
}

// ---------------- fallback (R5-proven fp32-gather kernel) ----------------
__global__ __launch_bounds__(256, 3)
void lp_main(const float* __restrict__ z,
             const int* __restrict__ ei32,
             const float* __restrict__ W1,
             const float* __restrict__ b1,
             const float* __restrict__ W2,
             const float* __restrict__ b2,
             float* __restrict__ out,
             const int* __restrict__ flag,
             const uint4* __restrict__ wpack,
             int use_ws, int E, int ntiles)
{
    __shared__ uint4 ldsA_[64 * 512 / 16];
    __shared__ float part[4][64];
    char* ldsc = (char*)ldsA_;

    const int t = threadIdx.x, lane = t & 63, w = t >> 6;
    const int use64 = flag[0];

    uint4 Bf[8][2];
    if (use_ws) {
        #pragma unroll
        for (int kc = 0; kc < 8; ++kc)
            #pragma unroll
            for (int js = 0; js < 2; ++js)
                Bf[kc][js] = wpack[(kc * 8 + (w * 2 + js)) * 64 + lane];
    } else {
        #pragma unroll
        for (int kc = 0; kc < 8; ++kc)
            #pragma unroll
            for (int js = 0; js < 2; ++js) {
                const int k0 = kc * 32 + (lane >> 4) * 8;
                const int j  = (w * 2 + js) * 16 + (lane & 15);
                unsigned wv[4];
                #pragma unroll
                for (int p = 0; p < 4; ++p)
                    wv[p] = pk2bf(W1[(k0 + 2 * p) * HID + j],
                                  W1[(k0 + 2 * p + 1) * HID + j]);
                Bf[kc][js] = make_uint4(wv[0], wv[1], wv[2], wv[3]);
            }
    }

    const int e_r = lane & 15, q = lane >> 4, m16 = q * 16;
    const float b1v0 = b1[w * 32 + e_r], b1v1 = b1[w * 32 + 16 + e_r];
    const float w2v0 = W2[w * 32 + e_r], w2v1 = W2[w * 32 + 16 + e_r];
    const float b2v  = b2[0];

    for (int tile = blockIdx.x; tile < ntiles; tile += gridDim.x) {
        const int e0 = tile * 64;
        #pragma unroll 8
        for (int i = 0; i < 16; ++i) {
            const int el = i * 4 + w;
            int e = e0 + el; if (e > E - 1) e = E - 1;
            const int word = (lane < 32) ? e : (E + e);
            int node = ei32[(long long)word << use64];
            node = min(max(node, 0), NN - 1);
            const float4 v = *reinterpret_cast<const float4*>(
                &z[node * IN_DIM + (lane & 31) * 4]);
            const int byte = el * 512 + ((lane * 8) ^ ((el & 7) << 4));
            *reinterpret_cast<uint2*>(ldsc + byte) =
                make_uint2(pk2bf(v.x, v.y), pk2bf(v.z, v.w));
        }
        __syncthreads();

        f32x4 acc[4][2] = {};
        #pragma unroll
        for (int kc = 0; kc < 8; ++kc) {
            #pragma unroll
            for (int es = 0; es < 4; ++es) {
                const int row  = es * 16 + e_r;
                const int byte = row * 512 + ((kc * 64 + m16) ^ ((row & 7) << 4));
                const bf16x8 a = *reinterpret_cast<const bf16x8*>(ldsc + byte);
                acc[es][0] = __builtin_amdgcn_mfma_f32_16x16x32_bf16(
                    a, asbf(Bf[kc][0]), acc[es][0], 0, 0, 0);
                acc[es][1] = __builtin_amdgcn_mfma_f32_16x16x32_bf16(
                    a, asbf(Bf[kc][1]), acc[es][1], 0, 0, 0);
            }
        }

        float v16[16];
        #pragma unroll
        for (int es = 0; es < 4; ++es)
            #pragma unroll
            for (int reg = 0; reg < 4; ++reg)
                v16[es * 4 + reg] = fmaxf(acc[es][0][reg] + b1v0, 0.f) * w2v0
                                  + fmaxf(acc[es][1][reg] + b1v1, 0.f) * w2v1;
        #pragma unroll
        for (int rnd = 0; rnd < 4; ++rnd) {
            const int o = 1 << rnd, hl = 8 >> rnd;
            #pragma unroll
            for (int i = 0; i < hl; ++i) {
                const float a = v16[i], b = v16[i + hl];
                const float s = (lane & o) ? a : b;
                const float r = __shfl_xor(s, o);
                v16[i] = ((lane & o) ? b : a) + r;
            }
        }
        {
            const int lx  = lane & 15;
            const int idx = ((lx & 1) << 3) | ((lx & 2) << 1) | ((lx & 4) >> 1) | ((lx & 8) >> 3);
            const int edge = (idx >> 2) * 16 + q * 4 + (idx & 3);
            part[w][edge] = v16[0];
        }
        __syncthreads();

        if (t < 64) {
            const int e = e0 + t;
            if (e < E) {
                const float s = part[0][t] + part[1][t] + part[2][t] + part[3][t] + b2v;
                out[e] = 1.f / (1.f + expf(-s));
            }
        }
    }
}

extern "C" void kernel_launch(void* const* d_in, const int* in_sizes, int n_in,
                              void* d_out, int out_size, void* d_ws, size_t ws_size,
                              hipStream_t stream) {
    const float* z  = (const float*)d_in[0];
    const void*  ei = d_in[1];
    const float* W1 = (const float*)d_in[2];
    const float* b1 = (const float*)d_in[3];
    const float* W2 = (const float*)d_in[4];
    const float* b2 = (const float*)d_in[5];
    float* out = (float*)d_out;
    int*   flag  = (int*)d_ws;
    uint4* wpack = (uint4*)((char*)d_ws + WPACK_OFF);
    char*  ubf   = (char*)d_ws + UBF_OFF;
    char*  vbf   = (char*)d_ws + VBF_OFF;

    const int E = in_sizes[1] / 2;
    const int use_ws = (ws_size >= (size_t)(WPACK_OFF + WPACK_BYTES)) ? 1 : 0;
    const int use_uv = (ws_size >= (size_t)(VBF_OFF + VBF_BYTES)) ? 1 : 0;

    hipLaunchKernelGGL(prep, dim3(16), dim3(256), 0, stream,
                       W1, (const unsigned*)ei, wpack, flag, use_ws);

    if (use_uv) {
        const int nwt = NN / 16;                           // 6250 tiles
        const int ngrp = (nwt + 3) / 4;                    // 1563 tile-groups
        hipLaunchKernelGGL(uv_gemm, dim3(ngrp * 2), dim3(256), 0, stream,
                           z, wpack, ubf, vbf, nwt);
        hipLaunchKernelGGL(lp_edge, dim3(2048), dim3(256), 0, stream,
                           ubf, vbf, (const int*)ei, b1, W2, b2, out, flag, E);
    } else {
        const int ntiles = (E + 63) / 64;
        const int grid = (ntiles < 768) ? ntiles : 768;
        hipLaunchKernelGGL(lp_main, dim3(grid), dim3(256), 0, stream,
                           z, (const int*)ei, W1, b1, W2, b2, out, flag, wpack,
                           use_ws, E, ntiles);
    }
}